// Round 2
// baseline (591.762 us; speedup 1.0000x reference)
//
#include <hip/hip_runtime.h>
#include <hip/hip_bf16.h>
#include <stdint.h>

// Problem constants
#define L_DIM 4096
#define B_DIM 32
#define H_DIM 512
#define M_DIM (L_DIM * B_DIM)  // 131072 rows of the fused GEMM
#define K_DIM H_DIM            // 512 reduction dim

typedef _Float16 half8 __attribute__((ext_vector_type(8)));
typedef __fp16 fp16x2 __attribute__((ext_vector_type(2)));  // cvt_pkrtz return type
typedef float floatx4 __attribute__((ext_vector_type(4)));

// tanh(x) = 1 - 2/(1 + e^{2x}), via hw exp2 + rcp (~1e-7 abs err, saturates correctly)
__device__ __forceinline__ float tanh_fast(float x) {
  float e = __builtin_amdgcn_exp2f(x * 2.88539008177793f);  // 2*log2(e)
  return 1.0f - 2.0f * __builtin_amdgcn_rcpf(e + 1.0f);
}

__device__ __forceinline__ uint2 pack4(const float4& f) {
  const fp16x2 p0 = __builtin_amdgcn_cvt_pkrtz(f.x, f.y);
  const fp16x2 p1 = __builtin_amdgcn_cvt_pkrtz(f.z, f.w);
  uint2 u;
  u.x = __builtin_bit_cast(unsigned, p0);
  u.y = __builtin_bit_cast(unsigned, p1);
  return u;
}

// ---------------------------------------------------------------------------
// Merged prep: blocks [0,128) build W2 (Wk fp16, MFMA-fragment-packed);
// blocks [128,160) compute q_proj (fp32, exact).
// W2 chunk c = ((kt*32 + nc)*4 + q)*16 + l15 holds Wk[k=kt*32+q*8+j][n=nc*16+l15].
__global__ __launch_bounds__(256) void prep_kernel(const float* __restrict__ query,
                                                   const float* __restrict__ W,
                                                   float* __restrict__ qp,
                                                   _Float16* __restrict__ W2) {
  if (blockIdx.x < 128) {
    // ---- wconv: Wk (=W[512:]) -> packed fp16 chunks
    const int t = blockIdx.x * 256 + threadIdx.x;  // [0, 32768) chunk index
    const int l15 = t & 15;
    const int q = (t >> 4) & 3;
    const int nc = (t >> 6) & 31;
    const int kt = t >> 11;
    const int n = nc * 16 + l15;
    const int kbase = H_DIM + kt * 32 + q * 8;  // Wk rows live at W[512 + k]
    half8 h;
#pragma unroll
    for (int j = 0; j < 8; ++j)
      h[j] = (_Float16)W[(size_t)(kbase + j) * H_DIM + n];
    *(half8*)(W2 + (size_t)t * 8) = h;
  } else if (threadIdx.x < 128) {
    // ---- qproj: q_proj[b][h] = sum_i query[b][i] * W[i][h]
    const int b = blockIdx.x - 128;
    const int h = threadIdx.x * 4;
    const float* qrow = query + b * H_DIM;
    float4 acc = make_float4(0.f, 0.f, 0.f, 0.f);
#pragma unroll 8
    for (int i = 0; i < K_DIM; ++i) {
      const float qv = qrow[i];
      const float4 w4 = *(const float4*)(W + (size_t)i * H_DIM + h);
      acc.x += qv * w4.x; acc.y += qv * w4.y;
      acc.z += qv * w4.z; acc.w += qv * w4.w;
    }
    *(float4*)(qp + (size_t)b * H_DIM + h) = acc;
  }
}

// ---------------------------------------------------------------------------
// Fused GEMM + tanh + v-dot. 128 rows x 512 cols per block (key read once),
// 512 threads = 8 waves, each wave owns a DISTINCT 64-col stripe (acc[8][4])
// so every W2 fragment is loaded exactly once per block.
// A: LDS double-buffer (fp16, padded stride 40), ONE barrier/iter; global A
// loads are lane-contiguous 16B and prefetched 2 iters ahead; staging uses
// VGPR+ds_write so s_barrier needs no vmcnt drain -- global loads stay in
// flight across it. B: global->VGPR direct (W2 packed per-fragment),
// prefetched 1 iter ahead, L2-resident.
__global__ __launch_bounds__(512, 2) void fused_gemm_kernel(
    const float* __restrict__ key, const _Float16* __restrict__ W2,
    const float* __restrict__ qp, const float* __restrict__ v,
    float* __restrict__ scores) {
  __shared__ __align__(16) _Float16 As[2][128 * 40];  // pad 32->40: frag reads ~2-way
  __shared__ float swave[8 * 128];

  const int tid = threadIdx.x;
  const int lane = tid & 63;
  const int wn = tid >> 6;        // wave id = column stripe [0,8)
  const int l15 = lane & 15;
  const int quad = lane >> 4;
  const int m0 = blockIdx.x * 128;

  // A staging: thread t loads 16B chunk (t&7) of rows (t>>3) and (t>>3)+64
  const int ar = tid >> 3;       // 0..63
  const int aseg = tid & 7;      // 16B chunk within 128B k-slice
  const float* ag0 = key + (size_t)(m0 + ar) * K_DIM + aseg * 4;
  const float* ag1 = ag0 + (size_t)64 * K_DIM;
  const int adst0 = ar * 40 + aseg * 4;          // halves
  const int adst1 = (ar + 64) * 40 + aseg * 4;

  // B: chunk index for (kt, fn) = (kt*32 + wn*4 + fn)*64 + lane; 16B chunks
  const half8* bptr = (const half8*)W2 + (size_t)(wn * 4) * 64 + lane;

  // fragment LDS offsets (8 row-groups of 16)
  int aoff[8];
#pragma unroll
  for (int fm = 0; fm < 8; ++fm) aoff[fm] = (fm * 16 + l15) * 40 + quad * 8;

  floatx4 acc[8][4];
#pragma unroll
  for (int fm = 0; fm < 8; ++fm)
#pragma unroll
    for (int fn = 0; fn < 4; ++fn) acc[fm][fn] = (floatx4)0.0f;

  // prologue: A(0) -> LDS buf0; issue A(1), B(0)
  float4 ra0 = *(const float4*)(ag0);
  float4 ra1 = *(const float4*)(ag1);
  half8 bn[4];
#pragma unroll
  for (int fn = 0; fn < 4; ++fn) bn[fn] = bptr[fn * 64];
  bptr += 32 * 64;
  *(uint2*)(As[0] + adst0) = pack4(ra0);
  *(uint2*)(As[0] + adst1) = pack4(ra1);
  ra0 = *(const float4*)(ag0 + 32);
  ra1 = *(const float4*)(ag1 + 32);
  __syncthreads();

  for (int kt = 0; kt < 16; ++kt) {
    half8 bc[4];
#pragma unroll
    for (int fn = 0; fn < 4; ++fn) bc[fn] = bn[fn];
    if (kt < 15) {
      // issue B(kt+1) now, consume next iteration
#pragma unroll
      for (int fn = 0; fn < 4; ++fn) bn[fn] = bptr[fn * 64];
      bptr += 32 * 64;
    }
    // frag reads for this iteration (buf kt&1, written before last barrier)
    half8 av[8];
#pragma unroll
    for (int fm = 0; fm < 8; ++fm) av[fm] = *(const half8*)(As[kt & 1] + aoff[fm]);
    if (kt < 15) {
      // stage A(kt+1) into the other buffer (raw regs issued 2 iters ago)
      _Float16* dst = As[(kt + 1) & 1];
      *(uint2*)(dst + adst0) = pack4(ra0);
      *(uint2*)(dst + adst1) = pack4(ra1);
      if (kt < 14) {
        ra0 = *(const float4*)(ag0 + (kt + 2) * 32);
        ra1 = *(const float4*)(ag1 + (kt + 2) * 32);
      }
    }
#pragma unroll
    for (int fm = 0; fm < 8; ++fm)
#pragma unroll
      for (int fn = 0; fn < 4; ++fn)
        acc[fm][fn] = __builtin_amdgcn_mfma_f32_16x16x32_f16(av[fm], bc[fn],
                                                             acc[fm][fn], 0, 0, 0);
    __syncthreads();  // lgkmcnt only: outstanding global loads cross freely
  }

  // Epilogue: score[m] = sum_n v[n] * tanh(qp[m&31][n] + kproj[m][n])
  // C/D layout: col = lane&15, row = quad*4 + reg (verified: passes)
  float vv[4];
#pragma unroll
  for (int fn = 0; fn < 4; ++fn) vv[fn] = v[wn * 64 + fn * 16 + l15];

#pragma unroll
  for (int fm = 0; fm < 8; ++fm) {
#pragma unroll
    for (int r = 0; r < 4; ++r) {
      const int mrow = fm * 16 + quad * 4 + r;
      const float* qrow = qp + (size_t)(mrow & 31) * H_DIM;
      float rs = 0.f;
#pragma unroll
      for (int fn = 0; fn < 4; ++fn) {
        const int n = wn * 64 + fn * 16 + l15;
        const float x = qrow[n] + acc[fm][fn][r];
        rs += vv[fn] * tanh_fast(x);
      }
      rs += __shfl_xor(rs, 1);
      rs += __shfl_xor(rs, 2);
      rs += __shfl_xor(rs, 4);
      rs += __shfl_xor(rs, 8);
      if (l15 == 0) swave[wn * 128 + mrow] = rs;
    }
  }
  __syncthreads();
  if (tid < 128) {
    float s = 0.f;
#pragma unroll
    for (int j = 0; j < 8; ++j) s += swave[j * 128 + tid];
    const int m = m0 + tid;  // m = l*32 + b
    scores[(size_t)(m & 31) * L_DIM + (m >> 5)] = s;  // transposed: [b][l]
  }
}

// ---------------------------------------------------------------------------
// softmax over l per b; scores already [b][l]; out[b][l] — fully coalesced.
// Wave shfl reductions: 2 barriers instead of 16.
__global__ __launch_bounds__(256) void softmax_kernel(const float* __restrict__ scores,
                                                      float* __restrict__ out) {
  const int b = blockIdx.x;
  const int t = threadIdx.x;
  const int lane = t & 63;
  const int w = t >> 6;
  __shared__ float redm[4], reds[4];
  const float* srow = scores + (size_t)b * L_DIM;
  float s[16];
#pragma unroll
  for (int i = 0; i < 16; ++i) s[i] = srow[t + i * 256];
  float mx = s[0];
#pragma unroll
  for (int i = 1; i < 16; ++i) mx = fmaxf(mx, s[i]);
#pragma unroll
  for (int off = 1; off < 64; off <<= 1) mx = fmaxf(mx, __shfl_xor(mx, off));
  if (lane == 0) redm[w] = mx;
  __syncthreads();
  mx = fmaxf(fmaxf(redm[0], redm[1]), fmaxf(redm[2], redm[3]));
  float sum = 0.f;
#pragma unroll
  for (int i = 0; i < 16; ++i) {
    s[i] = __builtin_amdgcn_exp2f((s[i] - mx) * 1.44269504f);
    sum += s[i];
  }
#pragma unroll
  for (int off = 1; off < 64; off <<= 1) sum += __shfl_xor(sum, off);
  if (lane == 0) reds[w] = sum;
  __syncthreads();
  const float inv = 1.0f / (reds[0] + reds[1] + reds[2] + reds[3]);
#pragma unroll
  for (int i = 0; i < 16; ++i) out[(size_t)b * L_DIM + t + i * 256] = s[i] * inv;
}

// ---------------------------------------------------------------------------
// PROBE ROUND: the full (idempotent) pipeline is launched TWICE. All kernels
// write deterministic outputs to the same buffers, so results are unchanged.
// dur_us(this) - dur_us(R1) == warm total kernel time T_prep+T_fused+T_softmax,
// which the top-5 rocprof view (all ~160us harness fills) cannot show us.
extern "C" void kernel_launch(void* const* d_in, const int* in_sizes, int n_in,
                              void* d_out, int out_size, void* d_ws, size_t ws_size,
                              hipStream_t stream) {
  const float* query = (const float*)d_in[0];
  const float* key   = (const float*)d_in[1];
  const float* W     = (const float*)d_in[2];
  const float* v     = (const float*)d_in[3];
  float* out = (float*)d_out;

  char* ws = (char*)d_ws;
  float* qp       = (float*)ws;                        // 32*512*4   = 64 KB
  float* scores   = (float*)(ws + 65536);              // 131072*4   = 512 KB
  _Float16* W2    = (_Float16*)(ws + 65536 + 524288);  // 512*512*2  = 512 KB

  for (int rep = 0; rep < 2; ++rep) {
    prep_kernel<<<160, 256, 0, stream>>>(query, W, qp, W2);
    fused_gemm_kernel<<<M_DIM / 128, 512, 0, stream>>>(key, W2, qp, v, scores);
    softmax_kernel<<<B_DIM, 256, 0, stream>>>(scores, out);
  }
}

// Round 3
// 440.237 us; speedup vs baseline: 1.3442x; 1.3442x over previous
//
#include <hip/hip_runtime.h>
#include <hip/hip_bf16.h>
#include <stdint.h>

// Problem constants
#define L_DIM 4096
#define B_DIM 32
#define H_DIM 512
#define M_DIM (L_DIM * B_DIM)  // 131072 rows of the fused GEMM
#define K_DIM H_DIM            // 512 reduction dim

typedef _Float16 half8 __attribute__((ext_vector_type(8)));
typedef __fp16 fp16x2 __attribute__((ext_vector_type(2)));  // cvt_pkrtz return type
typedef float floatx4 __attribute__((ext_vector_type(4)));

// tanh(x) = 1 - 2/(1 + e^{2x}), via hw exp2 + rcp (~1e-7 abs err, saturates correctly)
__device__ __forceinline__ float tanh_fast(float x) {
  float e = __builtin_amdgcn_exp2f(x * 2.88539008177793f);  // 2*log2(e)
  return 1.0f - 2.0f * __builtin_amdgcn_rcpf(e + 1.0f);
}

__device__ __forceinline__ uint2 pack4(const float4& f) {
  const fp16x2 p0 = __builtin_amdgcn_cvt_pkrtz(f.x, f.y);
  const fp16x2 p1 = __builtin_amdgcn_cvt_pkrtz(f.z, f.w);
  uint2 u;
  u.x = __builtin_bit_cast(unsigned, p0);
  u.y = __builtin_bit_cast(unsigned, p1);
  return u;
}

// async global->LDS DMA: 16B per lane, LDS dest = uniform base + lane*16
__device__ __forceinline__ void gload_lds16(const float* g, float* l) {
  __builtin_amdgcn_global_load_lds(
      (__attribute__((address_space(1))) void*)g,
      (__attribute__((address_space(3))) void*)l, 16, 0, 0);
}

// ---------------------------------------------------------------------------
// Merged prep (512 threads): blocks [0,64) build W2 (Wk fp16, fragment-packed);
// blocks [64,96) compute q_proj with 4-way K-split + LDS reduce.
// W2 chunk c = ((kt*32 + nc)*4 + q)*16 + l15 holds Wk[k=kt*32+q*8+j][n=nc*16+l15].
__global__ __launch_bounds__(512) void prep_kernel(const float* __restrict__ query,
                                                   const float* __restrict__ W,
                                                   float* __restrict__ qp,
                                                   _Float16* __restrict__ W2) {
  __shared__ float4 qred[512];
  if (blockIdx.x < 64) {
    // ---- wconv: Wk (=W[512:]) -> packed fp16 chunks
    const int t = blockIdx.x * 512 + threadIdx.x;  // [0, 32768) chunk index
    const int l15 = t & 15;
    const int q = (t >> 4) & 3;
    const int nc = (t >> 6) & 31;
    const int kt = t >> 11;
    const int n = nc * 16 + l15;
    const int kbase = H_DIM + kt * 32 + q * 8;  // Wk rows live at W[512 + k]
    half8 h;
#pragma unroll
    for (int j = 0; j < 8; ++j)
      h[j] = (_Float16)W[(size_t)(kbase + j) * H_DIM + n];
    *(half8*)(W2 + (size_t)t * 8) = h;
  } else {
    // ---- qproj: q_proj[b][h] = sum_i query[b][i] * W[i][h], 4-way K-split
    const int b = blockIdx.x - 64;
    const int tid = threadIdx.x;
    const int hx = tid & 127;       // h-column group
    const int ky = tid >> 7;        // K-chunk [0,4)
    const int h = hx * 4;
    const float* qrow = query + b * H_DIM + ky * 128;
    const float* wrow = W + (size_t)(ky * 128) * H_DIM + h;
    float4 acc = make_float4(0.f, 0.f, 0.f, 0.f);
#pragma unroll 8
    for (int i = 0; i < 128; ++i) {
      const float qv = qrow[i];
      const float4 w4 = *(const float4*)(wrow + (size_t)i * H_DIM);
      acc.x += qv * w4.x; acc.y += qv * w4.y;
      acc.z += qv * w4.z; acc.w += qv * w4.w;
    }
    qred[tid] = acc;
    __syncthreads();
    if (ky == 0) {
      const float4 a1 = qred[tid + 128], a2 = qred[tid + 256], a3 = qred[tid + 384];
      acc.x += a1.x + a2.x + a3.x;
      acc.y += a1.y + a2.y + a3.y;
      acc.z += a1.z + a2.z + a3.z;
      acc.w += a1.w + a2.w + a3.w;
      *(float4*)(qp + (size_t)b * H_DIM + h) = acc;
    }
  }
}

// ---------------------------------------------------------------------------
// Fused GEMM + tanh + v-dot. 128 rows x 512 cols per block, 8 waves each
// owning a 64-col stripe (every W2 fragment loaded once per block).
// A-path: async global_load_lds DMA into 3 fp32 LDS buffers (linear dest,
// SOURCE chunk pre-swizzled c^=(l>>3) so swizzled ds_read_b128 is ~2-way);
// prefetch distance 2 iters; counted s_waitcnt vmcnt(6) + raw s_barrier --
// vmcnt never drains to 0 in the main loop, loads stay in flight across
// barriers (T3/T4 pattern). A converted fp32->fp16 at fragment-read time.
// B: global->VGPR ping-pong (W2 packed per-fragment), 1 iter ahead, L2-hot.
__global__ __launch_bounds__(512, 2) void fused_gemm_kernel(
    const float* __restrict__ key, const _Float16* __restrict__ W2,
    const float* __restrict__ qp, const float* __restrict__ v,
    float* __restrict__ scores) {
  __shared__ __align__(16) float As[3][128 * 32];  // 3 x 16 KB k-slices, fp32
  __shared__ float swave[8 * 128];

  const int tid = threadIdx.x;
  const int lane = tid & 63;
  const int wn = tid >> 6;        // wave id = column stripe [0,8)
  const int l15 = lane & 15;
  const int quad = lane >> 4;
  const int m0 = blockIdx.x * 128;

  // A staging: wave wn segment j covers rows wn*16+j*8 .. +7; lane l holds
  // row wn*16+j*8+(l>>3), physical chunk (l&7) <- global chunk (l&7)^(l>>3)
  const int arow = wn * 16 + (lane >> 3);
  const int lc = (lane & 7) ^ (lane >> 3);
  const float* ag0 = key + (size_t)(m0 + arow) * K_DIM + lc * 4;
  const float* ag1 = ag0 + (size_t)8 * K_DIM;
  float* lb0 = &As[0][0] + (wn * 2 + 0) * 256;  // per-buffer wave segment bases
  float* lb1 = &As[0][0] + (wn * 2 + 1) * 256;  // (buffer = +4096 floats each)

  // B: chunk index for (kt, fn) = (kt*32 + wn*4 + fn)*64 + lane; 16B chunks
  const half8* bptr = (const half8*)W2 + (size_t)(wn * 4) * 64 + lane;

  floatx4 acc[8][4];
#pragma unroll
  for (int fm = 0; fm < 8; ++fm)
#pragma unroll
    for (int fn = 0; fn < 4; ++fn) acc[fm][fn] = (floatx4)0.0f;

  half8 bn[2][4];

  // prologue: stage A(0)->buf0, A(1)->buf1, issue B(0)
  gload_lds16(ag0, lb0);
  gload_lds16(ag1, lb1);
  gload_lds16(ag0 + 32, lb0 + 4096);
  gload_lds16(ag1 + 32, lb1 + 4096);
#pragma unroll
  for (int fn = 0; fn < 4; ++fn) bn[0][fn] = bptr[fn * 64];
  bptr += 32 * 64;

#pragma unroll
  for (int kt = 0; kt < 16; ++kt) {
    // retire A(kt)'s DMA (2 loads): newer = A(kt+1):2 + B(kt):4 = 6
    if (kt < 15) {
      asm volatile("s_waitcnt vmcnt(6)" ::: "memory");
    } else {
      asm volatile("s_waitcnt vmcnt(4)" ::: "memory");
    }
    __builtin_amdgcn_sched_barrier(0);
    __builtin_amdgcn_s_barrier();   // all waves' DMA for buf kt%3 now landed
    __builtin_amdgcn_sched_barrier(0);

    if (kt < 14) {
      // stage A(kt+2) -> buf (kt+2)%3 (read last iter; all waves past barrier)
      float* nb = lb0 + ((kt + 2) % 3) * 4096;
      gload_lds16(ag0 + (kt + 2) * 32, nb);
      gload_lds16(ag1 + (kt + 2) * 32, nb + 256);
    }
    if (kt < 15) {
#pragma unroll
      for (int fn = 0; fn < 4; ++fn) bn[(kt + 1) & 1][fn] = bptr[fn * 64];
      bptr += 32 * 64;
    }

    // fragment reads (swizzled) + fp32->fp16 pack
    const float* buf = &As[kt % 3][0];
    half8 av[8];
#pragma unroll
    for (int fm = 0; fm < 8; ++fm) {
      const int rbase = (fm * 16 + l15) * 32;
      const float4 f0 = *(const float4*)(buf + rbase + (((2 * quad + 0) ^ (l15 & 7)) * 4));
      const float4 f1 = *(const float4*)(buf + rbase + (((2 * quad + 1) ^ (l15 & 7)) * 4));
      const uint2 u0 = pack4(f0);
      const uint2 u1 = pack4(f1);
      const uint4 uu = make_uint4(u0.x, u0.y, u1.x, u1.y);
      av[fm] = __builtin_bit_cast(half8, uu);
    }
#pragma unroll
    for (int fm = 0; fm < 8; ++fm)
#pragma unroll
      for (int fn = 0; fn < 4; ++fn)
        acc[fm][fn] = __builtin_amdgcn_mfma_f32_16x16x32_f16(av[fm], bn[kt & 1][fn],
                                                             acc[fm][fn], 0, 0, 0);
  }

  // Epilogue: score[m] = sum_n v[n] * tanh(qp[m&31][n] + kproj[m][n])
  // C/D layout: col = lane&15, row = quad*4 + reg (verified: passes)
  float vv[4];
#pragma unroll
  for (int fn = 0; fn < 4; ++fn) vv[fn] = v[wn * 64 + fn * 16 + l15];

#pragma unroll
  for (int fm = 0; fm < 8; ++fm) {
#pragma unroll
    for (int r = 0; r < 4; ++r) {
      const int mrow = fm * 16 + quad * 4 + r;
      const float* qrow = qp + (size_t)(mrow & 31) * H_DIM;
      float rs = 0.f;
#pragma unroll
      for (int fn = 0; fn < 4; ++fn) {
        const int n = wn * 64 + fn * 16 + l15;
        const float x = qrow[n] + acc[fm][fn][r];
        rs += vv[fn] * tanh_fast(x);
      }
      rs += __shfl_xor(rs, 1);
      rs += __shfl_xor(rs, 2);
      rs += __shfl_xor(rs, 4);
      rs += __shfl_xor(rs, 8);
      if (l15 == 0) swave[wn * 128 + mrow] = rs;
    }
  }
  __syncthreads();
  if (tid < 128) {
    float s = 0.f;
#pragma unroll
    for (int j = 0; j < 8; ++j) s += swave[j * 128 + tid];
    const int m = m0 + tid;  // m = l*32 + b
    scores[(size_t)(m & 31) * L_DIM + (m >> 5)] = s;  // transposed: [b][l]
  }
}

// ---------------------------------------------------------------------------
// softmax over l per b; scores already [b][l]; out[b][l] — fully coalesced.
// Wave shfl reductions: 2 barriers instead of 16.
__global__ __launch_bounds__(256) void softmax_kernel(const float* __restrict__ scores,
                                                      float* __restrict__ out) {
  const int b = blockIdx.x;
  const int t = threadIdx.x;
  const int lane = t & 63;
  const int w = t >> 6;
  __shared__ float redm[4], reds[4];
  const float* srow = scores + (size_t)b * L_DIM;
  float s[16];
#pragma unroll
  for (int i = 0; i < 16; ++i) s[i] = srow[t + i * 256];
  float mx = s[0];
#pragma unroll
  for (int i = 1; i < 16; ++i) mx = fmaxf(mx, s[i]);
#pragma unroll
  for (int off = 1; off < 64; off <<= 1) mx = fmaxf(mx, __shfl_xor(mx, off));
  if (lane == 0) redm[w] = mx;
  __syncthreads();
  mx = fmaxf(fmaxf(redm[0], redm[1]), fmaxf(redm[2], redm[3]));
  float sum = 0.f;
#pragma unroll
  for (int i = 0; i < 16; ++i) {
    s[i] = __builtin_amdgcn_exp2f((s[i] - mx) * 1.44269504f);
    sum += s[i];
  }
#pragma unroll
  for (int off = 1; off < 64; off <<= 1) sum += __shfl_xor(sum, off);
  if (lane == 0) reds[w] = sum;
  __syncthreads();
  const float inv = 1.0f / (reds[0] + reds[1] + reds[2] + reds[3]);
#pragma unroll
  for (int i = 0; i < 16; ++i) out[(size_t)b * L_DIM + t + i * 256] = s[i] * inv;
}

// ---------------------------------------------------------------------------
extern "C" void kernel_launch(void* const* d_in, const int* in_sizes, int n_in,
                              void* d_out, int out_size, void* d_ws, size_t ws_size,
                              hipStream_t stream) {
  const float* query = (const float*)d_in[0];
  const float* key   = (const float*)d_in[1];
  const float* W     = (const float*)d_in[2];
  const float* v     = (const float*)d_in[3];
  float* out = (float*)d_out;

  char* ws = (char*)d_ws;
  float* qp       = (float*)ws;                        // 32*512*4   = 64 KB
  float* scores   = (float*)(ws + 65536);              // 131072*4   = 512 KB
  _Float16* W2    = (_Float16*)(ws + 65536 + 524288);  // 512*512*2  = 512 KB

  prep_kernel<<<96, 512, 0, stream>>>(query, W, qp, W2);
  fused_gemm_kernel<<<M_DIM / 128, 512, 0, stream>>>(key, W2, qp, v, scores);
  softmax_kernel<<<B_DIM, 256, 0, stream>>>(scores, out);
}

// Round 4
// 428.844 us; speedup vs baseline: 1.3799x; 1.0266x over previous
//
#include <hip/hip_runtime.h>
#include <hip/hip_bf16.h>
#include <stdint.h>

// Problem constants
#define L_DIM 4096
#define B_DIM 32
#define H_DIM 512
#define M_DIM (L_DIM * B_DIM)  // 131072 rows of the fused GEMM
#define K_DIM H_DIM            // 512 reduction dim

typedef _Float16 half8 __attribute__((ext_vector_type(8)));
typedef __fp16 fp16x2 __attribute__((ext_vector_type(2)));  // cvt_pkrtz return type
typedef float floatx4 __attribute__((ext_vector_type(4)));

// tanh(x) = 1 - 2/(1 + e^{2x}), via hw exp2 + rcp (~1e-7 abs err, saturates correctly)
__device__ __forceinline__ float tanh_fast(float x) {
  float e = __builtin_amdgcn_exp2f(x * 2.88539008177793f);  // 2*log2(e)
  return 1.0f - 2.0f * __builtin_amdgcn_rcpf(e + 1.0f);
}

__device__ __forceinline__ uint2 pack4(const float4& f) {
  const fp16x2 p0 = __builtin_amdgcn_cvt_pkrtz(f.x, f.y);
  const fp16x2 p1 = __builtin_amdgcn_cvt_pkrtz(f.z, f.w);
  uint2 u;
  u.x = __builtin_bit_cast(unsigned, p0);
  u.y = __builtin_bit_cast(unsigned, p1);
  return u;
}

// async global->LDS DMA: 16B per lane, LDS dest = uniform base + lane*16
__device__ __forceinline__ void gload_lds16(const float* g, float* l) {
  __builtin_amdgcn_global_load_lds(
      (__attribute__((address_space(1))) void*)g,
      (__attribute__((address_space(3))) void*)l, 16, 0, 0);
}

#define VM_WAIT(n) asm volatile("s_waitcnt vmcnt(" #n ")" ::: "memory")

// ---------------------------------------------------------------------------
// Merged prep (512 threads): blocks [0,64) build W2 (Wk fp16, fragment-packed);
// blocks [64,96) compute q_proj with 4-way K-split + LDS reduce.
// W2 chunk c = ((kt*32 + nc)*4 + q)*16 + l15 holds Wk[k=kt*32+q*8+j][n=nc*16+l15].
__global__ __launch_bounds__(512) void prep_kernel(const float* __restrict__ query,
                                                   const float* __restrict__ W,
                                                   float* __restrict__ qp,
                                                   _Float16* __restrict__ W2) {
  __shared__ float4 qred[512];
  if (blockIdx.x < 64) {
    // ---- wconv: Wk (=W[512:]) -> packed fp16 chunks
    const int t = blockIdx.x * 512 + threadIdx.x;  // [0, 32768) chunk index
    const int l15 = t & 15;
    const int q = (t >> 4) & 3;
    const int nc = (t >> 6) & 31;
    const int kt = t >> 11;
    const int n = nc * 16 + l15;
    const int kbase = H_DIM + kt * 32 + q * 8;  // Wk rows live at W[512 + k]
    half8 h;
#pragma unroll
    for (int j = 0; j < 8; ++j)
      h[j] = (_Float16)W[(size_t)(kbase + j) * H_DIM + n];
    *(half8*)(W2 + (size_t)t * 8) = h;
  } else {
    // ---- qproj: q_proj[b][h] = sum_i query[b][i] * W[i][h], 4-way K-split
    const int b = blockIdx.x - 64;
    const int tid = threadIdx.x;
    const int hx = tid & 127;       // h-column group
    const int ky = tid >> 7;        // K-chunk [0,4)
    const int h = hx * 4;
    const float* qrow = query + b * H_DIM + ky * 128;
    const float* wrow = W + (size_t)(ky * 128) * H_DIM + h;
    float4 acc = make_float4(0.f, 0.f, 0.f, 0.f);
#pragma unroll 8
    for (int i = 0; i < 128; ++i) {
      const float qv = qrow[i];
      const float4 w4 = *(const float4*)(wrow + (size_t)i * H_DIM);
      acc.x += qv * w4.x; acc.y += qv * w4.y;
      acc.z += qv * w4.z; acc.w += qv * w4.w;
    }
    qred[tid] = acc;
    __syncthreads();
    if (ky == 0) {
      const float4 a1 = qred[tid + 128], a2 = qred[tid + 256], a3 = qred[tid + 384];
      acc.x += a1.x + a2.x + a3.x;
      acc.y += a1.y + a2.y + a3.y;
      acc.z += a1.z + a2.z + a3.z;
      acc.w += a1.w + a2.w + a3.w;
      *(float4*)(qp + (size_t)b * H_DIM + h) = acc;
    }
  }
}

// ---------------------------------------------------------------------------
// Fused GEMM + tanh + v-dot, v2: 64 rows x 512 cols per block (acc=64 VGPR
// per lane -> 2 blocks/CU resident; two independent barrier domains per CU
// so one block's MFMA covers the other's barrier/LDS phase).
// A-path: async global_load_lds DMA into 4 rotating fp32 LDS buffers (8 KB
// each), prefetch distance 3 iters, exact counted s_waitcnt vmcnt(N) + raw
// s_barrier -- vmcnt never drains to 0 in the loop, loads stay in flight
// across barriers. Source chunks pre-swizzled c^=(row&7) so the swizzled
// ds_read_b128 fragment reads are ~2-way within a quad.
// B: global->VGPR ping-pong (W2 packed per-fragment), 1 iter ahead, L2-hot.
__global__ __launch_bounds__(512, 4) void fused_gemm_kernel(
    const float* __restrict__ key, const _Float16* __restrict__ W2,
    const float* __restrict__ qp, const float* __restrict__ v,
    float* __restrict__ scores) {
  __shared__ __align__(16) float As[4][64 * 32];  // 4 x 8 KB k-slices, fp32
  __shared__ float swave[8 * 64];

  const int tid = threadIdx.x;
  const int lane = tid & 63;
  const int wn = tid >> 6;        // wave id = column stripe [0,8)
  const int l15 = lane & 15;
  const int quad = lane >> 4;
  const int m0 = blockIdx.x * 64;

  // A staging: thread t covers row t>>3 (0..63), phys chunk t&7; source chunk
  // pre-swizzled (t&7)^(row&7). One DMA per wave per iter (8 rows x 128B).
  const int srow = tid >> 3;
  const int lc = (tid & 7) ^ (srow & 7);
  const float* ag = key + (size_t)(m0 + srow) * K_DIM + lc * 4;
  float* lbase = &As[0][0] + wn * 256;  // wave's uniform LDS dest (+2048/buf)

  // B: chunk index for (kt, fn) = (kt*32 + wn*4 + fn)*64 + lane; 16B chunks
  const half8* bptr = (const half8*)W2 + (size_t)(wn * 4) * 64 + lane;

  floatx4 acc[4][4];
#pragma unroll
  for (int fm = 0; fm < 4; ++fm)
#pragma unroll
    for (int fn = 0; fn < 4; ++fn) acc[fm][fn] = (floatx4)0.0f;

  half8 bn[2][4];

  // prologue: DMA A(0..2) -> buf0..2; issue B(0)
  gload_lds16(ag, lbase);
  gload_lds16(ag + 32, lbase + 2048);
  gload_lds16(ag + 64, lbase + 4096);
#pragma unroll
  for (int fn = 0; fn < 4; ++fn) bn[0][fn] = bptr[fn * 64];
  bptr += 32 * 64;

#pragma unroll
  for (int kt = 0; kt < 16; ++kt) {
    // retire A(kt)'s DMA: N = #VMEM issued after it (exact; never 0)
    if (kt == 0)       VM_WAIT(6);
    else if (kt == 1)  VM_WAIT(10);
    else if (kt == 14) VM_WAIT(13);
    else if (kt == 15) VM_WAIT(12);
    else               VM_WAIT(14);
    __builtin_amdgcn_sched_barrier(0);
    __builtin_amdgcn_s_barrier();   // all waves' DMA for buf kt&3 now landed
    __builtin_amdgcn_sched_barrier(0);

    if (kt < 13) {
      // stage A(kt+3) -> buf (kt+3)&3 (read at iter kt-1; all waves are past
      // that iter's reads once they crossed this barrier)
      gload_lds16(ag + (kt + 3) * 32, lbase + ((kt + 3) & 3) * 2048);
    }
    if (kt < 15) {
#pragma unroll
      for (int fn = 0; fn < 4; ++fn) bn[(kt + 1) & 1][fn] = bptr[fn * 64];
      bptr += 32 * 64;
    }

    // fragment reads (swizzled) + fp32->fp16 pack
    const float* buf = &As[kt & 3][0];
    half8 av[4];
#pragma unroll
    for (int fm = 0; fm < 4; ++fm) {
      const int rbase = (fm * 16 + l15) * 32;
      const float4 f0 = *(const float4*)(buf + rbase + (((2 * quad + 0) ^ (l15 & 7)) * 4));
      const float4 f1 = *(const float4*)(buf + rbase + (((2 * quad + 1) ^ (l15 & 7)) * 4));
      const uint2 u0 = pack4(f0);
      const uint2 u1 = pack4(f1);
      const uint4 uu = make_uint4(u0.x, u0.y, u1.x, u1.y);
      av[fm] = __builtin_bit_cast(half8, uu);
    }
#pragma unroll
    for (int fm = 0; fm < 4; ++fm)
#pragma unroll
      for (int fn = 0; fn < 4; ++fn)
        acc[fm][fn] = __builtin_amdgcn_mfma_f32_16x16x32_f16(av[fm], bn[kt & 1][fn],
                                                             acc[fm][fn], 0, 0, 0);
  }

  // Epilogue: score[m] = sum_n v[n] * tanh(qp[m&31][n] + kproj[m][n])
  // C/D layout: col = lane&15, row = quad*4 + reg (verified: passes)
  float vv[4];
#pragma unroll
  for (int fn = 0; fn < 4; ++fn) vv[fn] = v[wn * 64 + fn * 16 + l15];

#pragma unroll
  for (int fm = 0; fm < 4; ++fm) {
#pragma unroll
    for (int r = 0; r < 4; ++r) {
      const int mrow = fm * 16 + quad * 4 + r;
      const float* qrow = qp + (size_t)(mrow & 31) * H_DIM;
      float rs = 0.f;
#pragma unroll
      for (int fn = 0; fn < 4; ++fn) {
        const int n = wn * 64 + fn * 16 + l15;
        const float x = qrow[n] + acc[fm][fn][r];
        rs += vv[fn] * tanh_fast(x);
      }
      rs += __shfl_xor(rs, 1);
      rs += __shfl_xor(rs, 2);
      rs += __shfl_xor(rs, 4);
      rs += __shfl_xor(rs, 8);
      if (l15 == 0) swave[wn * 64 + mrow] = rs;
    }
  }
  __syncthreads();
  if (tid < 64) {
    float s = 0.f;
#pragma unroll
    for (int j = 0; j < 8; ++j) s += swave[j * 64 + tid];
    const int m = m0 + tid;  // m = l*32 + b
    scores[(size_t)(m & 31) * L_DIM + (m >> 5)] = s;  // transposed: [b][l]
  }
}

// ---------------------------------------------------------------------------
// softmax over l per b; scores already [b][l]; out[b][l] — fully coalesced.
// Wave shfl reductions: 2 barriers instead of 16.
__global__ __launch_bounds__(256) void softmax_kernel(const float* __restrict__ scores,
                                                      float* __restrict__ out) {
  const int b = blockIdx.x;
  const int t = threadIdx.x;
  const int lane = t & 63;
  const int w = t >> 6;
  __shared__ float redm[4], reds[4];
  const float* srow = scores + (size_t)b * L_DIM;
  float s[16];
#pragma unroll
  for (int i = 0; i < 16; ++i) s[i] = srow[t + i * 256];
  float mx = s[0];
#pragma unroll
  for (int i = 1; i < 16; ++i) mx = fmaxf(mx, s[i]);
#pragma unroll
  for (int off = 1; off < 64; off <<= 1) mx = fmaxf(mx, __shfl_xor(mx, off));
  if (lane == 0) redm[w] = mx;
  __syncthreads();
  mx = fmaxf(fmaxf(redm[0], redm[1]), fmaxf(redm[2], redm[3]));
  float sum = 0.f;
#pragma unroll
  for (int i = 0; i < 16; ++i) {
    s[i] = __builtin_amdgcn_exp2f((s[i] - mx) * 1.44269504f);
    sum += s[i];
  }
#pragma unroll
  for (int off = 1; off < 64; off <<= 1) sum += __shfl_xor(sum, off);
  if (lane == 0) reds[w] = sum;
  __syncthreads();
  const float inv = 1.0f / (reds[0] + reds[1] + reds[2] + reds[3]);
#pragma unroll
  for (int i = 0; i < 16; ++i) out[(size_t)b * L_DIM + t + i * 256] = s[i] * inv;
}

// ---------------------------------------------------------------------------
extern "C" void kernel_launch(void* const* d_in, const int* in_sizes, int n_in,
                              void* d_out, int out_size, void* d_ws, size_t ws_size,
                              hipStream_t stream) {
  const float* query = (const float*)d_in[0];
  const float* key   = (const float*)d_in[1];
  const float* W     = (const float*)d_in[2];
  const float* v     = (const float*)d_in[3];
  float* out = (float*)d_out;

  char* ws = (char*)d_ws;
  float* qp       = (float*)ws;                        // 32*512*4   = 64 KB
  float* scores   = (float*)(ws + 65536);              // 131072*4   = 512 KB
  _Float16* W2    = (_Float16*)(ws + 65536 + 524288);  // 512*512*2  = 512 KB

  prep_kernel<<<96, 512, 0, stream>>>(query, W, qp, W2);
  fused_gemm_kernel<<<M_DIM / 64, 512, 0, stream>>>(key, W2, qp, v, scores);
  softmax_kernel<<<B_DIM, 256, 0, stream>>>(scores, out);
}

// Round 5
// 422.235 us; speedup vs baseline: 1.4015x; 1.0157x over previous
//
#include <hip/hip_runtime.h>
#include <hip/hip_bf16.h>
#include <stdint.h>

// Problem constants
#define L_DIM 4096
#define B_DIM 32
#define H_DIM 512
#define M_DIM (L_DIM * B_DIM)  // 131072 rows of the fused GEMM
#define K_DIM H_DIM            // 512 reduction dim

typedef _Float16 half8 __attribute__((ext_vector_type(8)));
typedef __fp16 fp16x2 __attribute__((ext_vector_type(2)));  // cvt_pkrtz return type
typedef float floatx4 __attribute__((ext_vector_type(4)));

// tanh(x) = 1 - 2/(1 + e^{2x}), via hw exp2 + rcp (~1e-7 abs err, saturates correctly)
__device__ __forceinline__ float tanh_fast(float x) {
  float e = __builtin_amdgcn_exp2f(x * 2.88539008177793f);  // 2*log2(e)
  return 1.0f - 2.0f * __builtin_amdgcn_rcpf(e + 1.0f);
}

__device__ __forceinline__ uint2 pack4(const float4& f) {
  const fp16x2 p0 = __builtin_amdgcn_cvt_pkrtz(f.x, f.y);
  const fp16x2 p1 = __builtin_amdgcn_cvt_pkrtz(f.z, f.w);
  uint2 u;
  u.x = __builtin_bit_cast(unsigned, p0);
  u.y = __builtin_bit_cast(unsigned, p1);
  return u;
}

// ---------------------------------------------------------------------------
// Merged prep (512 threads): blocks [0,64) build W2 (Wk fp16, fragment-packed);
// blocks [64,96) compute q_proj with 4-way K-split + LDS reduce.
// W2 chunk c = ((kt*32 + nc)*4 + q)*16 + l15 holds Wk[k=kt*32+q*8+j][n=nc*16+l15].
__global__ __launch_bounds__(512) void prep_kernel(const float* __restrict__ query,
                                                   const float* __restrict__ W,
                                                   float* __restrict__ qp,
                                                   _Float16* __restrict__ W2) {
  __shared__ float4 qred[512];
  if (blockIdx.x < 64) {
    // ---- wconv: Wk (=W[512:]) -> packed fp16 chunks
    const int t = blockIdx.x * 512 + threadIdx.x;  // [0, 32768) chunk index
    const int l15 = t & 15;
    const int q = (t >> 4) & 3;
    const int nc = (t >> 6) & 31;
    const int kt = t >> 11;
    const int n = nc * 16 + l15;
    const int kbase = H_DIM + kt * 32 + q * 8;  // Wk rows live at W[512 + k]
    half8 h;
#pragma unroll
    for (int j = 0; j < 8; ++j)
      h[j] = (_Float16)W[(size_t)(kbase + j) * H_DIM + n];
    *(half8*)(W2 + (size_t)t * 8) = h;
  } else {
    // ---- qproj: q_proj[b][h] = sum_i query[b][i] * W[i][h], 4-way K-split
    const int b = blockIdx.x - 64;
    const int tid = threadIdx.x;
    const int hx = tid & 127;       // h-column group
    const int ky = tid >> 7;        // K-chunk [0,4)
    const int h = hx * 4;
    const float* qrow = query + b * H_DIM + ky * 128;
    const float* wrow = W + (size_t)(ky * 128) * H_DIM + h;
    float4 acc = make_float4(0.f, 0.f, 0.f, 0.f);
#pragma unroll 8
    for (int i = 0; i < 128; ++i) {
      const float qv = qrow[i];
      const float4 w4 = *(const float4*)(wrow + (size_t)i * H_DIM);
      acc.x += qv * w4.x; acc.y += qv * w4.y;
      acc.z += qv * w4.z; acc.w += qv * w4.w;
    }
    qred[tid] = acc;
    __syncthreads();
    if (ky == 0) {
      const float4 a1 = qred[tid + 128], a2 = qred[tid + 256], a3 = qred[tid + 384];
      acc.x += a1.x + a2.x + a3.x;
      acc.y += a1.y + a2.y + a3.y;
      acc.z += a1.z + a2.z + a3.z;
      acc.w += a1.w + a2.w + a3.w;
      *(float4*)(qp + (size_t)b * H_DIM + h) = acc;
    }
  }
}

// ---------------------------------------------------------------------------
// Fused GEMM + tanh + v-dot, v3: 64 rows x 512 cols per block, 8 col-stripe
// waves, 2 blocks/CU (VGPR budget <=128 via single-buffered B).
// A-path: reg-staged fp16 LDS double-buffer. Each thread loads ONE float4
// (prefetched 2 iters ahead, compiler-counted vmcnt), packs fp32->fp16 ONCE
// (2 cvt/thread/iter -- was 16/wave/iter duplicated 8x at read time), and
// ds_writes 8B. Fragment read = single ds_read_b128 per fm (4/wave/iter,
// was 8 + pack chain). Row stride 32 halves (64B): both write (4/bank) and
// read (8/bank) patterns are bank-uniform = LDS throughput floor.
// Sync: raw s_barrier + explicit lgkmcnt(0) only -- NO vmcnt drain, so A/B
// global loads stay in flight across barriers (compiler tracks their VGPR
// deps with exact counted waits).
// B: global->VGPR per-iter (W2 packed per-fragment), L2-hot; latency covered
// by 16 waves/CU TLP.
__global__ __launch_bounds__(512, 4) void fused_gemm_kernel(
    const float* __restrict__ key, const _Float16* __restrict__ W2,
    const float* __restrict__ qp, const float* __restrict__ v,
    float* __restrict__ scores) {
  __shared__ __align__(16) _Float16 As[2][64 * 32];  // 2 x 4 KB fp16 k-slices
  __shared__ float swave[8 * 64];

  const int tid = threadIdx.x;
  const int lane = tid & 63;
  const int wn = tid >> 6;        // wave id = column stripe [0,8)
  const int l15 = lane & 15;
  const int quad = lane >> 4;
  const int m0 = blockIdx.x * 64;

  // A staging: thread t covers row t>>3 (0..63), 16B k-chunk t&7
  const int srow = tid >> 3;
  const int schunk = tid & 7;
  const float* ag = key + (size_t)(m0 + srow) * K_DIM + schunk * 4;
  const int adst = srow * 32 + schunk * 4;  // halves

  // B: chunk index for (kt, fn) = (kt*32 + wn*4 + fn)*64 + lane; 16B chunks
  const half8* bptr = (const half8*)W2 + (size_t)(wn * 4) * 64 + lane;

  floatx4 acc[4][4];
#pragma unroll
  for (int fm = 0; fm < 4; ++fm)
#pragma unroll
    for (int fn = 0; fn < 4; ++fn) acc[fm][fn] = (floatx4)0.0f;

  // prologue: A(0) -> LDS buf0 directly; prefetch A(1), A(2) into regs
  float4 ra0 = *(const float4*)(ag);
  float4 rb[2];
  rb[1] = *(const float4*)(ag + 32);   // A(1), written in region 0
  rb[0] = *(const float4*)(ag + 64);   // A(2), written in region 1
  *(uint2*)(As[0] + adst) = pack4(ra0);
  asm volatile("s_waitcnt lgkmcnt(0)" ::: "memory");
  __builtin_amdgcn_s_barrier();
  __builtin_amdgcn_sched_barrier(0);

#pragma unroll
  for (int kt = 0; kt < 16; ++kt) {
    // B fragments for this iter (L2-resident; latency hidden by TLP)
    half8 bc[4];
#pragma unroll
    for (int fn = 0; fn < 4; ++fn) bc[fn] = bptr[fn * 64];
    bptr += 32 * 64;

    // A fragments from LDS buf kt&1 (single b128 per fm)
    const _Float16* buf = As[kt & 1];
    half8 av[4];
#pragma unroll
    for (int fm = 0; fm < 4; ++fm)
      av[fm] = *(const half8*)(buf + (fm * 16 + l15) * 32 + quad * 8);

    if (kt < 15) {
      // stage A(kt+1) into other buffer (reg loaded 2 regions ago)
      *(uint2*)(As[(kt + 1) & 1] + adst) = pack4(rb[(kt + 1) & 1]);
      if (kt < 13) rb[(kt + 1) & 1] = *(const float4*)(ag + (kt + 3) * 32);
    }

#pragma unroll
    for (int fm = 0; fm < 4; ++fm)
#pragma unroll
      for (int fn = 0; fn < 4; ++fn)
        acc[fm][fn] = __builtin_amdgcn_mfma_f32_16x16x32_f16(av[fm], bc[fn],
                                                             acc[fm][fn], 0, 0, 0);

    __builtin_amdgcn_sched_barrier(0);
    asm volatile("s_waitcnt lgkmcnt(0)" ::: "memory");  // own ds_writes landed
    __builtin_amdgcn_s_barrier();                        // all waves' writes landed
    __builtin_amdgcn_sched_barrier(0);
  }

  // Epilogue: score[m] = sum_n v[n] * tanh(qp[m&31][n] + kproj[m][n])
  // C/D layout: col = lane&15, row = quad*4 + reg (verified: passes)
  float vv[4];
#pragma unroll
  for (int fn = 0; fn < 4; ++fn) vv[fn] = v[wn * 64 + fn * 16 + l15];

#pragma unroll
  for (int fm = 0; fm < 4; ++fm) {
#pragma unroll
    for (int r = 0; r < 4; ++r) {
      const int mrow = fm * 16 + quad * 4 + r;
      const float* qrow = qp + (size_t)(mrow & 31) * H_DIM;
      float rs = 0.f;
#pragma unroll
      for (int fn = 0; fn < 4; ++fn) {
        const int n = wn * 64 + fn * 16 + l15;
        const float x = qrow[n] + acc[fm][fn][r];
        rs += vv[fn] * tanh_fast(x);
      }
      rs += __shfl_xor(rs, 1);
      rs += __shfl_xor(rs, 2);
      rs += __shfl_xor(rs, 4);
      rs += __shfl_xor(rs, 8);
      if (l15 == 0) swave[wn * 64 + mrow] = rs;
    }
  }
  __syncthreads();
  if (tid < 64) {
    float s = 0.f;
#pragma unroll
    for (int j = 0; j < 8; ++j) s += swave[j * 64 + tid];
    const int m = m0 + tid;  // m = l*32 + b
    scores[(size_t)(m & 31) * L_DIM + (m >> 5)] = s;  // transposed: [b][l]
  }
}

// ---------------------------------------------------------------------------
// softmax over l per b; scores already [b][l]; out[b][l] — fully coalesced.
// Wave shfl reductions: 2 barriers instead of 16.
__global__ __launch_bounds__(256) void softmax_kernel(const float* __restrict__ scores,
                                                      float* __restrict__ out) {
  const int b = blockIdx.x;
  const int t = threadIdx.x;
  const int lane = t & 63;
  const int w = t >> 6;
  __shared__ float redm[4], reds[4];
  const float* srow = scores + (size_t)b * L_DIM;
  float s[16];
#pragma unroll
  for (int i = 0; i < 16; ++i) s[i] = srow[t + i * 256];
  float mx = s[0];
#pragma unroll
  for (int i = 1; i < 16; ++i) mx = fmaxf(mx, s[i]);
#pragma unroll
  for (int off = 1; off < 64; off <<= 1) mx = fmaxf(mx, __shfl_xor(mx, off));
  if (lane == 0) redm[w] = mx;
  __syncthreads();
  mx = fmaxf(fmaxf(redm[0], redm[1]), fmaxf(redm[2], redm[3]));
  float sum = 0.f;
#pragma unroll
  for (int i = 0; i < 16; ++i) {
    s[i] = __builtin_amdgcn_exp2f((s[i] - mx) * 1.44269504f);
    sum += s[i];
  }
#pragma unroll
  for (int off = 1; off < 64; off <<= 1) sum += __shfl_xor(sum, off);
  if (lane == 0) reds[w] = sum;
  __syncthreads();
  const float inv = 1.0f / (reds[0] + reds[1] + reds[2] + reds[3]);
#pragma unroll
  for (int i = 0; i < 16; ++i) out[(size_t)b * L_DIM + t + i * 256] = s[i] * inv;
}

// ---------------------------------------------------------------------------
extern "C" void kernel_launch(void* const* d_in, const int* in_sizes, int n_in,
                              void* d_out, int out_size, void* d_ws, size_t ws_size,
                              hipStream_t stream) {
  const float* query = (const float*)d_in[0];
  const float* key   = (const float*)d_in[1];
  const float* W     = (const float*)d_in[2];
  const float* v     = (const float*)d_in[3];
  float* out = (float*)d_out;

  char* ws = (char*)d_ws;
  float* qp       = (float*)ws;                        // 32*512*4   = 64 KB
  float* scores   = (float*)(ws + 65536);              // 131072*4   = 512 KB
  _Float16* W2    = (_Float16*)(ws + 65536 + 524288);  // 512*512*2  = 512 KB

  prep_kernel<<<96, 512, 0, stream>>>(query, W, qp, W2);
  fused_gemm_kernel<<<M_DIM / 64, 512, 0, stream>>>(key, W2, qp, v, scores);
  softmax_kernel<<<B_DIM, 256, 0, stream>>>(scores, out);
}